// Round 1
// baseline (49.891 us; speedup 1.0000x reference)
//
#include <hip/hip_runtime.h>
#include <math.h>

#define IMG    512
#define IMG2   (IMG*IMG)
#define NBATCH 32
#define TC 64          // output cols per tile
#define TR 32          // output rows per tile
#define ECC 72         // extended cols (TC + 8)
#define V5P 361        // V5 row pitch in floats (72*5 + 1; 361 % 32 == 9)
#define NBLOCKS ((IMG/TC)*(IMG/TR)*NBATCH)   // 8*16*32 = 4096
#define NPIX 8388608.0f

__global__ __launch_bounds__(256)
void lncc_main(const float* __restrict__ Tm, const float* __restrict__ Im,
               float* __restrict__ partial)
{
    __shared__ float V5[TR][V5P];   // column sums: [out_row][ec*5 + q], 46.2 KB
    __shared__ float wsum[4];

    const int tid = threadIdx.x;
    const int x0 = blockIdx.x * TC;
    const int y0 = blockIdx.y * TR;
    const size_t base = (size_t)blockIdx.z * IMG2;

    // ---------- Pass 1: vertical sliding 9-sums of {I, J, I2, J2, IJ} ----------
    // 216 threads: 72 extended columns x 3 row-strips (11,11,10 output rows).
    if (tid < 3 * ECC) {
        const int ec    = tid % ECC;
        const int strip = tid / ECC;          // 0,1,2
        const int r0    = strip * 11;         // first output row of strip
        const int nout  = (strip == 2) ? 10 : 11;
        const int gx    = x0 + ec - 4;
        const bool xok  = (unsigned)gx < IMG;

        float tring[9], iring[9];             // raw-value ring (static idx via unroll)
        float w0 = 0.f, w1 = 0.f, w2 = 0.f, w3 = 0.f, w4 = 0.f;

        #pragma unroll
        for (int j = 0; j < 19; ++j) {
            const int gy = y0 + r0 + j - 4;
            float t = 0.f, v = 0.f;
            if (xok && (unsigned)gy < IMG) {
                const size_t off = base + (size_t)gy * IMG + (size_t)gx;
                t = Tm[off];
                v = Im[off];
            }
            w0 += t; w1 += v;
            w2 = fmaf(t, t, w2);
            w3 = fmaf(v, v, w3);
            w4 = fmaf(t, v, w4);
            tring[j % 9] = t;
            iring[j % 9] = v;
            if (j >= 8) {
                const int k = j - 8;                 // strip-local output row
                if (k < nout) {
                    float* dst = &V5[r0 + k][ec * 5];
                    dst[0] = w0; dst[1] = w1; dst[2] = w2; dst[3] = w3; dst[4] = w4;
                }
                const int o = (j - 8) % 9;           // compile-time after unroll
                const float tr_ = tring[o], ir_ = iring[o];
                w0 -= tr_; w1 -= ir_;
                w2 = fmaf(-tr_, tr_, w2);
                w3 = fmaf(-ir_, ir_, w3);
                w4 = fmaf(-tr_, ir_, w4);
            }
        }
    }
    __syncthreads();

    // ---------- Pass 2: horizontal sliding 9-sums + score ----------
    // 256 threads: 32 output rows x 8 column segments (8 output cols each).
    float lsum = 0.f;
    {
        const int row = tid & 31;              // output row within tile
        const int seg = tid >> 5;              // 0..7
        const int cb  = seg * 8;               // first output col of segment
        const float* src = &V5[row][0];

        float ring[9][5];
        float W0 = 0.f, W1 = 0.f, W2 = 0.f, W3 = 0.f, W4 = 0.f;

        #pragma unroll
        for (int k = 0; k < 16; ++k) {
            const float* s5 = src + (cb + k) * 5;
            const float h0 = s5[0], h1 = s5[1], h2 = s5[2], h3 = s5[3], h4 = s5[4];
            const int ri = k % 9;
            ring[ri][0] = h0; ring[ri][1] = h1; ring[ri][2] = h2;
            ring[ri][3] = h3; ring[ri][4] = h4;
            W0 += h0; W1 += h1; W2 += h2; W3 += h3; W4 += h4;
            if (k >= 8) {
                const float inv81 = 1.0f / 81.0f;
                const float uI = W0 * inv81;
                const float uJ = W1 * inv81;
                const float cross = W4 - uJ * W0 - uI * W1 + uI * uJ * 81.0f;
                const float Iv = W2 - 2.0f * uI * W0 + uI * uI * 81.0f;
                const float Jv = W3 - 2.0f * uJ * W1 + uJ * uJ * 81.0f;
                lsum += cross / (sqrtf(Iv) * sqrtf(Jv) + 1e-6f);
                const int o = (k - 8) % 9;
                W0 -= ring[o][0]; W1 -= ring[o][1]; W2 -= ring[o][2];
                W3 -= ring[o][3]; W4 -= ring[o][4];
            }
        }
    }

    // ---------- deterministic block reduction ----------
    #pragma unroll
    for (int off = 32; off >= 1; off >>= 1)
        lsum += __shfl_down(lsum, off, 64);
    if ((tid & 63) == 0) wsum[tid >> 6] = lsum;
    __syncthreads();
    if (tid == 0) {
        const int bid = (blockIdx.z * gridDim.y + blockIdx.y) * gridDim.x + blockIdx.x;
        partial[bid] = wsum[0] + wsum[1] + wsum[2] + wsum[3];
    }
}

__global__ __launch_bounds__(256)
void lncc_reduce(const float* __restrict__ partial, float* __restrict__ out)
{
    __shared__ float wsum[4];
    const int tid = threadIdx.x;
    float s = 0.f;
    for (int i = tid; i < NBLOCKS; i += 256) s += partial[i];
    #pragma unroll
    for (int off = 32; off >= 1; off >>= 1)
        s += __shfl_down(s, off, 64);
    if ((tid & 63) == 0) wsum[tid >> 6] = s;
    __syncthreads();
    if (tid == 0) out[0] = 1.0f - (wsum[0] + wsum[1] + wsum[2] + wsum[3]) / NPIX;
}

extern "C" void kernel_launch(void* const* d_in, const int* in_sizes, int n_in,
                              void* d_out, int out_size, void* d_ws, size_t ws_size,
                              hipStream_t stream)
{
    (void)in_sizes; (void)n_in; (void)out_size; (void)ws_size;
    const float* Tm = (const float*)d_in[0];   // template
    const float* Im = (const float*)d_in[1];   // image
    float* out = (float*)d_out;
    float* part = (float*)d_ws;                // 4096 floats of scratch

    dim3 grid(IMG / TC, IMG / TR, NBATCH);     // (8, 16, 32)
    lncc_main<<<grid, 256, 0, stream>>>(Tm, Im, part);
    lncc_reduce<<<1, 256, 0, stream>>>(part, out);
}